// Round 1
// baseline (391.271 us; speedup 1.0000x reference)
//
#include <hip/hip_runtime.h>
#include <math.h>

#define DDIM 4096
#define NPAT 16384
#define THRESHOLD 0.8f

// Kernel 1: gated = sigmoid(query @ W^T + b)
// One 64-lane wave per output element d. W row d is contiguous (D floats).
// Each lane reads 16 float4 -> 64 floats; total 4096 = D.
__global__ __launch_bounds__(256) void gate_kernel(
    const float* __restrict__ query,
    const float* __restrict__ W,
    const float* __restrict__ b,
    float* __restrict__ gated)
{
    int gtid = blockIdx.x * blockDim.x + threadIdx.x;
    int wave = gtid >> 6;          // output row index d
    int lane = threadIdx.x & 63;
    if (wave >= DDIM) return;

    const float4* Wrow = (const float4*)(W + (size_t)wave * DDIM);
    const float4* q4   = (const float4*)query;

    float sum = 0.0f;
#pragma unroll
    for (int i = 0; i < 16; ++i) {
        int idx = lane + i * 64;          // float4 index within row (0..1023)
        float4 w = Wrow[idx];
        float4 q = q4[idx];
        sum += w.x * q.x + w.y * q.y + w.z * q.z + w.w * q.w;
    }
    // wave-64 shuffle reduction
#pragma unroll
    for (int off = 32; off > 0; off >>= 1)
        sum += __shfl_down(sum, off, 64);

    if (lane == 0) {
        float x = sum + b[wave];
        gated[wave] = 1.0f / (1.0f + __expf(-x));
    }
}

// Kernel 2: sims[n] = 1 - mean(|memory[n] - gated|); mask[n] = sims[n] >= 0.8
// One 256-thread block per pattern row. Each thread: 4 float4 loads.
__global__ __launch_bounds__(256) void sims_kernel(
    const float* __restrict__ memory,
    const float* __restrict__ gated,
    float* __restrict__ sims,
    float* __restrict__ mask)
{
    int n = blockIdx.x;
    int t = threadIdx.x;

    const float4* mrow = (const float4*)(memory + (size_t)n * DDIM);
    const float4* g4   = (const float4*)gated;

    float sum = 0.0f;
#pragma unroll
    for (int i = 0; i < 4; ++i) {
        int idx = t + i * 256;            // float4 index (0..1023)
        float4 m = mrow[idx];
        float4 g = g4[idx];
        sum += fabsf(m.x - g.x) + fabsf(m.y - g.y)
             + fabsf(m.z - g.z) + fabsf(m.w - g.w);
    }

    // wave-64 shuffle reduction
#pragma unroll
    for (int off = 32; off > 0; off >>= 1)
        sum += __shfl_down(sum, off, 64);

    __shared__ float ws[4];
    int wid  = t >> 6;
    int lane = t & 63;
    if (lane == 0) ws[wid] = sum;
    __syncthreads();

    if (t == 0) {
        float s = ws[0] + ws[1] + ws[2] + ws[3];
        float sim = 1.0f - s * (1.0f / (float)DDIM);
        sims[n] = sim;
        mask[n] = (sim >= THRESHOLD) ? 1.0f : 0.0f;
    }
}

extern "C" void kernel_launch(void* const* d_in, const int* in_sizes, int n_in,
                              void* d_out, int out_size, void* d_ws, size_t ws_size,
                              hipStream_t stream) {
    const float* query  = (const float*)d_in[0];   // [1, D]
    const float* W      = (const float*)d_in[1];   // [D, D]
    const float* b      = (const float*)d_in[2];   // [D]
    const float* memory = (const float*)d_in[3];   // [N, D]

    float* gated = (float*)d_ws;                   // D floats scratch
    float* sims  = (float*)d_out;                  // first N floats
    float* mask  = (float*)d_out + NPAT;           // next N floats (0.0/1.0)

    // Kernel 1: D waves = D*64 threads
    {
        int threads = 256;
        int blocks  = (DDIM * 64) / threads;       // 1024
        gate_kernel<<<blocks, threads, 0, stream>>>(query, W, b, gated);
    }
    // Kernel 2: one block per pattern
    {
        sims_kernel<<<NPAT, 256, 0, stream>>>(memory, gated, sims, mask);
    }
}